// Round 2
// 462.243 us; speedup vs baseline: 1.0868x; 1.0868x over previous
//
#include <hip/hip_runtime.h>

typedef __attribute__((ext_vector_type(8))) short short8;
typedef __attribute__((ext_vector_type(4))) short short4_;
typedef __attribute__((ext_vector_type(4))) float float4_;

// ---- geometry ----
// B=65536 rows, FULL=1024, E=64 experts (W=16 -> HID=64 -> 32 -> 1), gate 1024->32->64.
// 16 groups x 4 experts. Per-group prepacked MFMA A-fragments (bf16) in d_ws:
//   A1 (W1^T, K padded 16->32, lanes<32 only): 4e*4mt*32l*8  = 4096 us (8192 B)
//   A2 (W2^T, permuted-K half-slots):          4e*2mt*4c*64l*4 = 8192 us (16384 B)
//   Ag (gw1_slice^T, full density):            2mt*2kc*64l*8 = 2048 us (4096 B)
// group block = 14336 ushorts (28672 B); tail: gw2p (permuted-K) 2048 us.
#define NGROUP 16
#define EPG 4
#define GBLK_US 14336
#define OFF_A2_US 4096
#define OFF_AG_US 12288
#define OFF_TAIL_US 229376   // 16*14336
#define N_A1 65536
#define N_A2 131072
#define N_AG 32768
#define N_TOT 231424         // + gw2p 2048

// R2: 128 rows/block, grid 512 -> 2 blocks/CU co-resident (LDS ~45KB/block),
// 16 waves/CU instead of 8. Each wave owns ONE 16-row tile.
// NOTE: R1's v_cvt_pk_bf16_f32 experiment FAILED numerics (absmax 2.8e-3 vs
// 3e-4 threshold -> non-RNE rounding); all bf16 packing uses scalar RNE f2bf.
#define ROWS_PB 128
#define STASH_LD 130   // padded leading dim: breaks the 8-way q-group bank conflict

__device__ __forceinline__ unsigned short f2bf(float f) {
  unsigned u = __builtin_bit_cast(unsigned, f);
  u += 0x7FFFu + ((u >> 16) & 1u);          // RNE
  return (unsigned short)(u >> 16);
}
__device__ __forceinline__ float bf2f(unsigned short s) {
  unsigned u = ((unsigned)s) << 16;
  return __builtin_bit_cast(float, u);
}
__device__ __forceinline__ float4_ MFMA(short8 a, short8 b, float4_ c) {
  return __builtin_amdgcn_mfma_f32_16x16x32_bf16(a, b, c, 0, 0, 0);
}
__device__ __forceinline__ float4_ relu4(float4_ v) {
  v[0] = fmaxf(v[0], 0.f); v[1] = fmaxf(v[1], 0.f);
  v[2] = fmaxf(v[2], 0.f); v[3] = fmaxf(v[3], 0.f);
  return v;
}
__device__ __forceinline__ short8 swap32(short8 v) {   // lane <-> lane^32
  union { short8 s; int i[4]; } u; u.s = v;
#pragma unroll
  for (int k = 0; k < 4; ++k) u.i[k] = __shfl_xor(u.i[k], 32);
  return u.s;
}

// ---------------- prepack kernel ----------------
__global__ void moe_setup(const float* __restrict__ gw1,
                          const float* __restrict__ gw2,
                          const float* __restrict__ ew1,
                          const float* __restrict__ ew2,
                          unsigned short* __restrict__ wsp)
{
  for (int i = blockIdx.x * blockDim.x + threadIdx.x; i < N_TOT;
       i += gridDim.x * blockDim.x) {
    if (i < N_A1) {                       // A1: a = ((e*4+mt)*32+l)*8+j, lanes 0..31
      int g = i >> 12, a = i & 4095;
      int j = a & 7, l = (a >> 3) & 31, mt = (a >> 8) & 3, e = (a >> 10) & 3;
      int k = ((l >> 4) << 3) + j;        // quad(0/1)*8+j  -> K in [0,16)
      int h = 16 * mt + (l & 15);
      int E = g * 4 + e;
      wsp[g * GBLK_US + a] = f2bf(ew1[(E * 16 + k) * 64 + h]);   // W1^T[h][k]
    } else if (i < N_A1 + N_A2) {         // A2: b = (((e*2+mt2)*4+c)*64+l)*4+j
      int i2 = i - N_A1;
      int g = i2 >> 13, b = i2 & 8191;
      int j = b & 3, l = (b >> 2) & 63, c = (b >> 8) & 3, mt2 = (b >> 10) & 1, e = (b >> 11) & 3;
      int q = l >> 4;
      int h1 = 16 * c + 4 * q + j;        // permuted-K slot (q, j<4) <-> h1
      int h2 = 16 * mt2 + (l & 15);
      int E = g * 4 + e;
      wsp[g * GBLK_US + OFF_A2_US + b] = f2bf(ew2[(E * 64 + h1) * 32 + h2]); // W2^T[h2][h1]
    } else if (i < N_A1 + N_A2 + N_AG) {  // Ag: a = ((mt*2+kc)*64+l)*8+j
      int i3 = i - (N_A1 + N_A2);
      int g = i3 >> 11, a = i3 & 2047;
      int j = a & 7, l = (a >> 3) & 63, kc = (a >> 9) & 1, mt = (a >> 10) & 1;
      int q = l >> 4;
      int col = g * 64 + kc * 32 + q * 8 + j;
      int gh = 16 * mt + (l & 15);
      wsp[g * GBLK_US + OFF_AG_US + a] = f2bf(gw1[col * 32 + gh]);  // gw1^T[gh][col]
    } else {                              // gw2p: d = ((mt3*2+c)*64+l)*4+j
      int d = i - (N_A1 + N_A2 + N_AG);
      int j = d & 3, l = (d >> 2) & 63, c = (d >> 8) & 1, mt3 = (d >> 9) & 3;
      int q = l >> 4;
      int gh = 16 * c + 4 * q + j;        // permuted-K slot <-> gh
      int e = 16 * mt3 + (l & 15);
      wsp[OFF_TAIL_US + d] = f2bf(gw2[gh * 64 + e]);                // gw2^T[e][gh]
    }
  }
}

// ---------------- main fused kernel ----------------
// grid 512 x 512 threads. WG handles 128 rows; wave w: rows [wg*128+w*16, +16).
// 2 blocks/CU co-resident (45KB LDS each) -> barrier stalls of one block overlap the other.
__global__ __launch_bounds__(512, 4) void moe_main(
    const float* __restrict__ x,
    const float* __restrict__ gb1,
    const float* __restrict__ gb2,
    const float* __restrict__ eb1,
    const float* __restrict__ eb2,
    const float* __restrict__ ew3,
    const float* __restrict__ eb3,
    const unsigned short* __restrict__ wsp,
    float* __restrict__ out)
{
  __shared__ __align__(16) unsigned short sStage[GBLK_US];       // 28672 B
  __shared__ unsigned short sStash[64 * STASH_LD];               // logits bf16 [e][row] 16640 B

  const int tid = threadIdx.x;
  const int wave = tid >> 6;
  const int lane = tid & 63;
  const int q = lane >> 4;
  const int n = lane & 15;
  const int wrow = wave * 16;
  const size_t rowBase0 = (size_t)blockIdx.x * ROWS_PB + wrow;

  const short8 zero8 = {0, 0, 0, 0, 0, 0, 0, 0};

  float4_ cg[2];   // gate pre-act accumulator, persists across all 16 stages
  cg[0] = (float4_){0.f, 0.f, 0.f, 0.f};
  cg[1] = (float4_){0.f, 0.f, 0.f, 0.f};

  for (int g = 0; g < NGROUP; ++g) {
    __syncthreads();
    {   // stage this group's prepacked fragments into LDS (1792 x 16B)
      const uint4* src = (const uint4*)(wsp + (size_t)g * GBLK_US);
      uint4* dst = (uint4*)sStage;
#pragma unroll
      for (int it = 0; it < 4; ++it) {
        int idx = tid + it * 512;
        if (idx < 1792) dst[idx] = src[idx];
      }
    }
    __syncthreads();

    // x fragments, full density (B-frag: [k=quad*8+j][n=lane15]); shared by gate + experts
    short8 bx[2];
#pragma unroll
    for (int kc = 0; kc < 2; ++kc) {
      const float* px = x + (rowBase0 + n) * 1024 + g * 64 + kc * 32 + q * 8;
      float4_ f0 = *(const float4_*)px;
      float4_ f1 = *(const float4_*)(px + 4);
      short8 v;
      v[0] = f2bf(f0[0]); v[1] = f2bf(f0[1]); v[2] = f2bf(f0[2]); v[3] = f2bf(f0[3]);
      v[4] = f2bf(f1[0]); v[5] = f2bf(f1[1]); v[6] = f2bf(f1[2]); v[7] = f2bf(f1[3]);
      bx[kc] = v;
    }

    // gate partial: cg += gw1_slice^T * x_slice^T
#pragma unroll
    for (int m = 0; m < 2; ++m)
#pragma unroll
      for (int kc = 0; kc < 2; ++kc) {
        short8 a = *(const short8*)(sStage + OFF_AG_US + ((m * 2 + kc) * 64 + lane) * 8);
        cg[m] = MFMA(a, bx[kc], cg[m]);
      }

    for (int e = 0; e < EPG; ++e) {
      const int E = g * EPG + e;
      // B1 from bx: even expert = quads0/1 of bx[kc]; odd = quads2/3 (xor-32 shuffle)
      short8 b1 = bx[e >> 1];
      if (e & 1) b1 = swap32(b1);
      b1 = (lane < 32) ? b1 : zero8;

      // layer 1: H1^T = W1^T * X^T (+eb1 via C init), K padded to 32
      float4_ c1[4];
#pragma unroll
      for (int m = 0; m < 4; ++m)
        c1[m] = *(const float4_*)(eb1 + E * 64 + 16 * m + 4 * q);
#pragma unroll
      for (int m = 0; m < 4; ++m) {
        short8 a1 = zero8;
        if (lane < 32) a1 = *(const short8*)(sStage + ((e * 4 + m) * 32 + lane) * 8);
        c1[m] = MFMA(a1, b1, c1[m]);
      }
#pragma unroll
      for (int m = 0; m < 4; ++m) c1[m] = relu4(c1[m]);

      // layer 2: H2^T = W2^T * H1^T (permuted-K half slots; C1 frag feeds B directly)
      float4_ c2[2];
#pragma unroll
      for (int m = 0; m < 2; ++m)
        c2[m] = *(const float4_*)(eb2 + E * 32 + 16 * m + 4 * q);
#pragma unroll
      for (int c = 0; c < 4; ++c) {
        short8 b2 = zero8;
        b2[0] = f2bf(c1[c][0]); b2[1] = f2bf(c1[c][1]);
        b2[2] = f2bf(c1[c][2]); b2[3] = f2bf(c1[c][3]);
#pragma unroll
        for (int m = 0; m < 2; ++m) {
          short4_ lo = *(const short4_*)(sStage + OFF_A2_US + (((e * 2 + m) * 4 + c) * 64 + lane) * 4);
          short8 a2 = {lo[0], lo[1], lo[2], lo[3], 0, 0, 0, 0};
          c2[m] = MFMA(a2, b2, c2[m]);
        }
      }
      // layer 3 (VALU dot + cross-quad reduce), stash logit as bf16
      float p = 0.f;
#pragma unroll
      for (int m = 0; m < 2; ++m) {
        float4_ cc = relu4(c2[m]);
        float4_ w3v = *(const float4_*)(ew3 + E * 32 + 16 * m + 4 * q);
        p += cc[0] * w3v[0] + cc[1] * w3v[1] + cc[2] * w3v[2] + cc[3] * w3v[3];
      }
      p += __shfl_xor(p, 16);
      p += __shfl_xor(p, 32);
      p += eb3[E];
      if (lane < 16) sStash[E * STASH_LD + wrow + lane] = f2bf(p);
    }
  }

  // ---- epilogue: finish gate, softmax, combine (wave-private stash, no barrier) ----
  short8 bg[2];
#pragma unroll
  for (int c = 0; c < 2; ++c) {
    float4_ gv = *(const float4_*)(gb1 + 16 * c + 4 * q);
    float4_ v = cg[c];
    v[0] = fmaxf(v[0] + gv[0], 0.f); v[1] = fmaxf(v[1] + gv[1], 0.f);
    v[2] = fmaxf(v[2] + gv[2], 0.f); v[3] = fmaxf(v[3] + gv[3], 0.f);
    short8 pv = zero8;
    pv[0] = f2bf(v[0]); pv[1] = f2bf(v[1]); pv[2] = f2bf(v[2]); pv[3] = f2bf(v[3]);
    bg[c] = pv;
  }
  float4_ c3[4];
#pragma unroll
  for (int m = 0; m < 4; ++m)
    c3[m] = *(const float4_*)(gb2 + 16 * m + 4 * q);
#pragma unroll
  for (int m = 0; m < 4; ++m)
#pragma unroll
    for (int c = 0; c < 2; ++c) {
      short4_ lo = *(const short4_*)(wsp + OFF_TAIL_US + ((m * 2 + c) * 64 + lane) * 4);
      short8 a = {lo[0], lo[1], lo[2], lo[3], 0, 0, 0, 0};
      c3[m] = MFMA(a, bg[c], c3[m]);
    }
  // softmax over 64 experts (spread across 4 quads x 16 per-lane values)
  float mx = -1e30f;
#pragma unroll
  for (int m = 0; m < 4; ++m) {
    mx = fmaxf(mx, c3[m][0]); mx = fmaxf(mx, c3[m][1]);
    mx = fmaxf(mx, c3[m][2]); mx = fmaxf(mx, c3[m][3]);
  }
  mx = fmaxf(mx, __shfl_xor(mx, 16));
  mx = fmaxf(mx, __shfl_xor(mx, 32));
  float s = 0.f, o = 0.f;
#pragma unroll
  for (int m = 0; m < 4; ++m)
#pragma unroll
    for (int i = 0; i < 4; ++i) {
      int e = 16 * m + 4 * q + i;
      float w = __expf(c3[m][i] - mx);
      s += w;
      o += w * bf2f(sStash[e * STASH_LD + wrow + n]);
    }
  s += __shfl_xor(s, 16);
  s += __shfl_xor(s, 32);
  o += __shfl_xor(o, 16);
  o += __shfl_xor(o, 32);
  if (lane < 16) out[rowBase0 + lane] = o / s;
}

extern "C" void kernel_launch(void* const* d_in, const int* in_sizes, int n_in,
                              void* d_out, int out_size, void* d_ws, size_t ws_size,
                              hipStream_t stream) {
  const float* x   = (const float*)d_in[0];
  const float* gw1 = (const float*)d_in[1];
  const float* gb1 = (const float*)d_in[2];
  const float* gw2 = (const float*)d_in[3];
  const float* gb2 = (const float*)d_in[4];
  const float* ew1 = (const float*)d_in[5];
  const float* eb1 = (const float*)d_in[6];
  const float* ew2 = (const float*)d_in[7];
  const float* eb2 = (const float*)d_in[8];
  const float* ew3 = (const float*)d_in[9];
  const float* eb3 = (const float*)d_in[10];
  unsigned short* wsp = (unsigned short*)d_ws;
  float* out = (float*)d_out;

  moe_setup<<<256, 256, 0, stream>>>(gw1, gw2, ew1, ew2, wsp);
  moe_main<<<512, 512, 0, stream>>>(x, gb1, gb2, eb1, eb2, ew3, eb3, wsp, out);
}

// Round 3
// 450.877 us; speedup vs baseline: 1.1142x; 1.0252x over previous
//
#include <hip/hip_runtime.h>

typedef __attribute__((ext_vector_type(8))) short short8;
typedef __attribute__((ext_vector_type(4))) short short4_;
typedef __attribute__((ext_vector_type(4))) float float4_;

// ---- geometry ----
// B=65536 rows, FULL=1024, E=64 experts (W=16 -> HID=64 -> 32 -> 1), gate 1024->32->64.
// 16 groups x 4 experts. Per-group prepacked MFMA A-fragments (bf16) in d_ws:
//   A1 (W1^T, K padded 16->32, lanes<32 only): 4e*4mt*32l*8  = 4096 us (8192 B)
//   A2 (W2^T, permuted-K half-slots):          4e*2mt*4c*64l*4 = 8192 us (16384 B)
//   Ag (gw1_slice^T, full density):            2mt*2kc*64l*8 = 2048 us (4096 B)
// group block = 14336 ushorts (28672 B); tail: gw2p (permuted-K) 2048 us.
#define NGROUP 16
#define EPG 4
#define GBLK_US 14336
#define OFF_A2_US 4096
#define OFF_AG_US 12288
#define OFF_TAIL_US 229376   // 16*14336
#define N_A1 65536
#define N_A2 131072
#define N_AG 32768
#define N_TOT 231424         // + gw2p 2048

// R3: 64 rows/block, 256 threads (4 waves), grid 1024 -> 4 blocks/CU co-resident
// (LDS 37.1KB/block). Same 16 waves/CU as R2 but 4 independent barrier domains:
// a block stalled at its barrier drain is covered by 3 others at other phases.
// x loads hoisted above the staging barrier so HBM latency drains there.
// NOTE R1 lesson: v_cvt_pk_bf16_f32 is NOT RNE-equivalent (absmax 2.8e-3) -> f2bf only.
// NOTE R2 lesson: SQ_LDS_BANK_CONFLICT=131072 is ~0.1% of cycles — not a lever.
#define ROWS_PB 64
#define STASH_LD 66    // 64 rows + pad; q-groups land on banks {0,4,8,12} in epilogue

__device__ __forceinline__ unsigned short f2bf(float f) {
  unsigned u = __builtin_bit_cast(unsigned, f);
  u += 0x7FFFu + ((u >> 16) & 1u);          // RNE
  return (unsigned short)(u >> 16);
}
__device__ __forceinline__ float bf2f(unsigned short s) {
  unsigned u = ((unsigned)s) << 16;
  return __builtin_bit_cast(float, u);
}
__device__ __forceinline__ float4_ MFMA(short8 a, short8 b, float4_ c) {
  return __builtin_amdgcn_mfma_f32_16x16x32_bf16(a, b, c, 0, 0, 0);
}
__device__ __forceinline__ float4_ relu4(float4_ v) {
  v[0] = fmaxf(v[0], 0.f); v[1] = fmaxf(v[1], 0.f);
  v[2] = fmaxf(v[2], 0.f); v[3] = fmaxf(v[3], 0.f);
  return v;
}
__device__ __forceinline__ short8 swap32(short8 v) {   // lane <-> lane^32
  union { short8 s; int i[4]; } u; u.s = v;
#pragma unroll
  for (int k = 0; k < 4; ++k) u.i[k] = __shfl_xor(u.i[k], 32);
  return u.s;
}

// ---------------- prepack kernel ----------------
__global__ void moe_setup(const float* __restrict__ gw1,
                          const float* __restrict__ gw2,
                          const float* __restrict__ ew1,
                          const float* __restrict__ ew2,
                          unsigned short* __restrict__ wsp)
{
  for (int i = blockIdx.x * blockDim.x + threadIdx.x; i < N_TOT;
       i += gridDim.x * blockDim.x) {
    if (i < N_A1) {                       // A1: a = ((e*4+mt)*32+l)*8+j, lanes 0..31
      int g = i >> 12, a = i & 4095;
      int j = a & 7, l = (a >> 3) & 31, mt = (a >> 8) & 3, e = (a >> 10) & 3;
      int k = ((l >> 4) << 3) + j;        // quad(0/1)*8+j  -> K in [0,16)
      int h = 16 * mt + (l & 15);
      int E = g * 4 + e;
      wsp[g * GBLK_US + a] = f2bf(ew1[(E * 16 + k) * 64 + h]);   // W1^T[h][k]
    } else if (i < N_A1 + N_A2) {         // A2: b = (((e*2+mt2)*4+c)*64+l)*4+j
      int i2 = i - N_A1;
      int g = i2 >> 13, b = i2 & 8191;
      int j = b & 3, l = (b >> 2) & 63, c = (b >> 8) & 3, mt2 = (b >> 10) & 1, e = (b >> 11) & 3;
      int q = l >> 4;
      int h1 = 16 * c + 4 * q + j;        // permuted-K slot (q, j<4) <-> h1
      int h2 = 16 * mt2 + (l & 15);
      int E = g * 4 + e;
      wsp[g * GBLK_US + OFF_A2_US + b] = f2bf(ew2[(E * 64 + h1) * 32 + h2]); // W2^T[h2][h1]
    } else if (i < N_A1 + N_A2 + N_AG) {  // Ag: a = ((mt*2+kc)*64+l)*8+j
      int i3 = i - (N_A1 + N_A2);
      int g = i3 >> 11, a = i3 & 2047;
      int j = a & 7, l = (a >> 3) & 63, kc = (a >> 9) & 1, mt = (a >> 10) & 1;
      int q = l >> 4;
      int col = g * 64 + kc * 32 + q * 8 + j;
      int gh = 16 * mt + (l & 15);
      wsp[g * GBLK_US + OFF_AG_US + a] = f2bf(gw1[col * 32 + gh]);  // gw1^T[gh][col]
    } else {                              // gw2p: d = ((mt3*2+c)*64+l)*4+j
      int d = i - (N_A1 + N_A2 + N_AG);
      int j = d & 3, l = (d >> 2) & 63, c = (d >> 8) & 1, mt3 = (d >> 9) & 3;
      int q = l >> 4;
      int gh = 16 * c + 4 * q + j;        // permuted-K slot <-> gh
      int e = 16 * mt3 + (l & 15);
      wsp[OFF_TAIL_US + d] = f2bf(gw2[gh * 64 + e]);                // gw2^T[e][gh]
    }
  }
}

// ---------------- main fused kernel ----------------
// grid 1024 x 256 threads. WG handles 64 rows; wave w: rows [wg*64+w*16, +16).
// 4 blocks/CU co-resident (37.1KB LDS each).
__global__ __launch_bounds__(256, 4) void moe_main(
    const float* __restrict__ x,
    const float* __restrict__ gb1,
    const float* __restrict__ gb2,
    const float* __restrict__ eb1,
    const float* __restrict__ eb2,
    const float* __restrict__ ew3,
    const float* __restrict__ eb3,
    const unsigned short* __restrict__ wsp,
    float* __restrict__ out)
{
  __shared__ __align__(16) unsigned short sStage[GBLK_US];       // 28672 B
  __shared__ unsigned short sStash[64 * STASH_LD];               // logits bf16 [e][row] 8448 B

  const int tid = threadIdx.x;
  const int wave = tid >> 6;
  const int lane = tid & 63;
  const int q = lane >> 4;
  const int n = lane & 15;
  const int wrow = wave * 16;
  const size_t rowBase0 = (size_t)blockIdx.x * ROWS_PB + wrow;

  const short8 zero8 = {0, 0, 0, 0, 0, 0, 0, 0};

  float4_ cg[2];   // gate pre-act accumulator, persists across all 16 stages
  cg[0] = (float4_){0.f, 0.f, 0.f, 0.f};
  cg[1] = (float4_){0.f, 0.f, 0.f, 0.f};

  for (int g = 0; g < NGROUP; ++g) {
    // issue x loads early: independent of LDS, latency drains at the staging
    // barrier (which waits vmcnt(0) anyway) instead of after it.
    float4_ xf[4];
#pragma unroll
    for (int kc = 0; kc < 2; ++kc) {
      const float* px = x + (rowBase0 + n) * 1024 + g * 64 + kc * 32 + q * 8;
      xf[kc * 2]     = *(const float4_*)px;
      xf[kc * 2 + 1] = *(const float4_*)(px + 4);
    }

    __syncthreads();
    {   // stage this group's prepacked fragments into LDS (1792 x 16B = 7*256)
      const uint4* src = (const uint4*)(wsp + (size_t)g * GBLK_US);
      uint4* dst = (uint4*)sStage;
#pragma unroll
      for (int it = 0; it < 7; ++it) {
        int idx = tid + it * 256;
        dst[idx] = src[idx];
      }
    }
    __syncthreads();

    // pack x fragments (B-frag: [k=quad*8+j][n=lane15]); shared by gate + experts
    short8 bx[2];
#pragma unroll
    for (int kc = 0; kc < 2; ++kc) {
      float4_ f0 = xf[kc * 2], f1 = xf[kc * 2 + 1];
      short8 v;
      v[0] = f2bf(f0[0]); v[1] = f2bf(f0[1]); v[2] = f2bf(f0[2]); v[3] = f2bf(f0[3]);
      v[4] = f2bf(f1[0]); v[5] = f2bf(f1[1]); v[6] = f2bf(f1[2]); v[7] = f2bf(f1[3]);
      bx[kc] = v;
    }

    // gate partial: cg += gw1_slice^T * x_slice^T
#pragma unroll
    for (int m = 0; m < 2; ++m)
#pragma unroll
      for (int kc = 0; kc < 2; ++kc) {
        short8 a = *(const short8*)(sStage + OFF_AG_US + ((m * 2 + kc) * 64 + lane) * 8);
        cg[m] = MFMA(a, bx[kc], cg[m]);
      }

    for (int e = 0; e < EPG; ++e) {
      const int E = g * EPG + e;
      // B1 from bx: even expert = quads0/1 of bx[kc]; odd = quads2/3 (xor-32 shuffle)
      short8 b1 = bx[e >> 1];
      if (e & 1) b1 = swap32(b1);
      b1 = (lane < 32) ? b1 : zero8;

      // layer 1: H1^T = W1^T * X^T (+eb1 via C init), K padded to 32
      float4_ c1[4];
#pragma unroll
      for (int m = 0; m < 4; ++m)
        c1[m] = *(const float4_*)(eb1 + E * 64 + 16 * m + 4 * q);
#pragma unroll
      for (int m = 0; m < 4; ++m) {
        short8 a1 = zero8;
        if (lane < 32) a1 = *(const short8*)(sStage + ((e * 4 + m) * 32 + lane) * 8);
        c1[m] = MFMA(a1, b1, c1[m]);
      }
#pragma unroll
      for (int m = 0; m < 4; ++m) c1[m] = relu4(c1[m]);

      // layer 2: H2^T = W2^T * H1^T (permuted-K half slots; C1 frag feeds B directly)
      float4_ c2[2];
#pragma unroll
      for (int m = 0; m < 2; ++m)
        c2[m] = *(const float4_*)(eb2 + E * 32 + 16 * m + 4 * q);
#pragma unroll
      for (int c = 0; c < 4; ++c) {
        short8 b2 = zero8;
        b2[0] = f2bf(c1[c][0]); b2[1] = f2bf(c1[c][1]);
        b2[2] = f2bf(c1[c][2]); b2[3] = f2bf(c1[c][3]);
#pragma unroll
        for (int m = 0; m < 2; ++m) {
          short4_ lo = *(const short4_*)(sStage + OFF_A2_US + (((e * 2 + m) * 4 + c) * 64 + lane) * 4);
          short8 a2 = {lo[0], lo[1], lo[2], lo[3], 0, 0, 0, 0};
          c2[m] = MFMA(a2, b2, c2[m]);
        }
      }
      // layer 3 (VALU dot + cross-quad reduce), stash logit as bf16
      float p = 0.f;
#pragma unroll
      for (int m = 0; m < 2; ++m) {
        float4_ cc = relu4(c2[m]);
        float4_ w3v = *(const float4_*)(ew3 + E * 32 + 16 * m + 4 * q);
        p += cc[0] * w3v[0] + cc[1] * w3v[1] + cc[2] * w3v[2] + cc[3] * w3v[3];
      }
      p += __shfl_xor(p, 16);
      p += __shfl_xor(p, 32);
      p += eb3[E];
      if (lane < 16) sStash[E * STASH_LD + wrow + lane] = f2bf(p);
    }
  }

  // ---- epilogue: finish gate, softmax, combine (wave-private stash, no barrier) ----
  short8 bg[2];
#pragma unroll
  for (int c = 0; c < 2; ++c) {
    float4_ gv = *(const float4_*)(gb1 + 16 * c + 4 * q);
    float4_ v = cg[c];
    v[0] = fmaxf(v[0] + gv[0], 0.f); v[1] = fmaxf(v[1] + gv[1], 0.f);
    v[2] = fmaxf(v[2] + gv[2], 0.f); v[3] = fmaxf(v[3] + gv[3], 0.f);
    short8 pv = zero8;
    pv[0] = f2bf(v[0]); pv[1] = f2bf(v[1]); pv[2] = f2bf(v[2]); pv[3] = f2bf(v[3]);
    bg[c] = pv;
  }
  float4_ c3[4];
#pragma unroll
  for (int m = 0; m < 4; ++m)
    c3[m] = *(const float4_*)(gb2 + 16 * m + 4 * q);
#pragma unroll
  for (int m = 0; m < 4; ++m)
#pragma unroll
    for (int c = 0; c < 2; ++c) {
      short4_ lo = *(const short4_*)(wsp + OFF_TAIL_US + ((m * 2 + c) * 64 + lane) * 4);
      short8 a = {lo[0], lo[1], lo[2], lo[3], 0, 0, 0, 0};
      c3[m] = MFMA(a, bg[c], c3[m]);
    }
  // softmax over 64 experts (spread across 4 quads x 16 per-lane values)
  float mx = -1e30f;
#pragma unroll
  for (int m = 0; m < 4; ++m) {
    mx = fmaxf(mx, c3[m][0]); mx = fmaxf(mx, c3[m][1]);
    mx = fmaxf(mx, c3[m][2]); mx = fmaxf(mx, c3[m][3]);
  }
  mx = fmaxf(mx, __shfl_xor(mx, 16));
  mx = fmaxf(mx, __shfl_xor(mx, 32));
  float s = 0.f, o = 0.f;
#pragma unroll
  for (int m = 0; m < 4; ++m)
#pragma unroll
    for (int i = 0; i < 4; ++i) {
      int e = 16 * m + 4 * q + i;
      float w = __expf(c3[m][i] - mx);
      s += w;
      o += w * bf2f(sStash[e * STASH_LD + wrow + n]);
    }
  s += __shfl_xor(s, 16);
  s += __shfl_xor(s, 32);
  o += __shfl_xor(o, 16);
  o += __shfl_xor(o, 32);
  if (lane < 16) out[rowBase0 + lane] = o / s;
}

extern "C" void kernel_launch(void* const* d_in, const int* in_sizes, int n_in,
                              void* d_out, int out_size, void* d_ws, size_t ws_size,
                              hipStream_t stream) {
  const float* x   = (const float*)d_in[0];
  const float* gw1 = (const float*)d_in[1];
  const float* gb1 = (const float*)d_in[2];
  const float* gw2 = (const float*)d_in[3];
  const float* gb2 = (const float*)d_in[4];
  const float* ew1 = (const float*)d_in[5];
  const float* eb1 = (const float*)d_in[6];
  const float* ew2 = (const float*)d_in[7];
  const float* eb2 = (const float*)d_in[8];
  const float* ew3 = (const float*)d_in[9];
  const float* eb3 = (const float*)d_in[10];
  unsigned short* wsp = (unsigned short*)d_ws;
  float* out = (float*)d_out;

  moe_setup<<<512, 256, 0, stream>>>(gw1, gw2, ew1, ew2, wsp);
  moe_main<<<1024, 256, 0, stream>>>(x, gb1, gb2, eb1, eb2, ew3, eb3, wsp, out);
}